// Round 12
// baseline (280.075 us; speedup 1.0000x reference)
//
#include <hip/hip_runtime.h>
#include <hip/hip_bf16.h>
#include <stddef.h>

#define NN 50000
#define EE 800000
#define DDIM 128
#define CAP 64                    // bucket capacity (Poisson(16): P(deg>64) ~ 3e-20)

// k_prep grid partition: feat-cast | weight-conv | bucket-CSR fill
#define CAST_BLOCKS 3125          // NN*DDIM/8 / 256 exactly
#define WCONV_BLOCKS 32           // 4*128*128/8 / 256 exactly
#define FILL_BLOCKS 782           // ceil(EE/4/256)
#define PREP_BLOCKS (CAST_BLOCKS + WCONV_BLOCKS + FILL_BLOCKS)

typedef short bf16x8 __attribute__((ext_vector_type(8)));
typedef float f32x4  __attribute__((ext_vector_type(4)));

__device__ __forceinline__ float bf2f(unsigned short u) {
  union { unsigned int i; float f; } v; v.i = ((unsigned int)u) << 16; return v.f;
}
__device__ __forceinline__ unsigned short f2bf(float f) {
  __hip_bfloat16 h = __float2bfloat16(f);
  return *reinterpret_cast<unsigned short*>(&h);
}
__device__ __forceinline__ uint4 pack8(const float4 a, const float4 b) {
  uint4 o;
  o.x = f2bf(a.x) | ((unsigned)f2bf(a.y) << 16);
  o.y = f2bf(a.z) | ((unsigned)f2bf(a.w) << 16);
  o.z = f2bf(b.x) | ((unsigned)f2bf(b.y) << 16);
  o.w = f2bf(b.z) | ((unsigned)f2bf(b.w) << 16);
  return o;
}

// ---------------- prep: feat cast || weight conversion || bucket-CSR fill ----------------
// The latency-bound fill section overlaps with the BW-bound cast on the same CUs.
// cnt must be pre-zeroed (hipMemsetAsync before this kernel).
__global__ __launch_bounds__(256) void k_prep(const float* __restrict__ feat,
                                              const float* __restrict__ w1a,
                                              const float* __restrict__ w1b,
                                              const float* __restrict__ w2a,
                                              const float* __restrict__ w2b,
                                              const int* __restrict__ src,
                                              const int* __restrict__ dst,
                                              unsigned short* __restrict__ Xb,
                                              unsigned short* __restrict__ W16,
                                              int* __restrict__ cnt,
                                              int* __restrict__ csr)
{
  const int b = blockIdx.x, tid = threadIdx.x;
  if (b < CAST_BLOCKS) {
    int t = b * 256 + tid;                       // 800000 exact
    const float4* p = reinterpret_cast<const float4*>(feat) + (size_t)t * 2;
    reinterpret_cast<uint4*>(Xb)[t] = pack8(p[0], p[1]);
  } else if (b < CAST_BLOCKS + WCONV_BLOCKS) {
    int i = (b - CAST_BLOCKS) * 256 + tid;       // 0..8191, 8 floats each
    int which = i >> 11, off = i & 2047;
    const float* wp = (which == 0) ? w1a : (which == 1) ? w1b : (which == 2) ? w2a : w2b;
    const float4* p = reinterpret_cast<const float4*>(wp + off * 8);
    reinterpret_cast<uint4*>(W16 + which * 16384)[off] = pack8(p[0], p[1]);
  } else {
    int t = (b - CAST_BLOCKS - WCONV_BLOCKS) * 256 + tid;
    if (t < EE / 4) {
      int4 s4 = reinterpret_cast<const int4*>(src)[t];
      int4 d4 = reinterpret_cast<const int4*>(dst)[t];
      int p;
      p = atomicAdd(&cnt[d4.x], 1); csr[(d4.x << 6) + p] = s4.x;
      p = atomicAdd(&cnt[d4.y], 1); csr[(d4.y << 6) + p] = s4.y;
      p = atomicAdd(&cnt[d4.z], 1); csr[(d4.z << 6) + p] = s4.z;
      p = atomicAdd(&cnt[d4.w], 1); csr[(d4.w << 6) + p] = s4.w;
    }
  }
}

// ---------------- fused GIN layer: agg + Linear->ReLU->Linear [+relu] ----------------
// 128 nodes/block, 512 threads = 8 waves. Wave w owns rows w*16..w*16+15:
//   phase A: aggregate its 16 nodes (4 neighbor rows per uint4 gather, butterfly
//            reduce, + (1+eps)*self), write bf16 rows into AH (swizzled) — wave-local.
//   GEMM1:   A from AH (own rows), B = Wa from WL; epilogue relu -> AH (own rows).
//   GEMM2:   A from AH, B = Wb from WL; epilogue -> global.
// A/H tile never crosses waves => only 3 block-wide syncs (WL staging).
template<int RELU_OUT, int BF16_OUT>
__global__ __launch_bounds__(512) void k_fused(const unsigned short* __restrict__ Xin,
                                               const int* __restrict__ cnt,
                                               const int* __restrict__ csr,
                                               const float* __restrict__ eps,
                                               const unsigned short* __restrict__ zrow,
                                               const unsigned short* __restrict__ Wa16,
                                               const float* __restrict__ Ba,
                                               const unsigned short* __restrict__ Wb16,
                                               const float* __restrict__ Bb,
                                               void* __restrict__ Yout)
{
  __shared__ unsigned short WL[128 * 128];   // weights (Wa, then Wb)
  __shared__ unsigned short AH[128 * 128];   // agg rows, then hidden rows
  const int tid = threadIdx.x;
  const int row0 = blockIdx.x * 128;
  const int w = tid >> 6, lane = tid & 63;
  const int g = lane >> 4;          // edge-slot group / k-granule q-role
  const int c = lane & 15;          // column chunk (8 bf16 = 16B)

  // stage Wa (issue early; agg hides the latency)
  #pragma unroll
  for (int i = 0; i < 4; ++i) {
    int gi = tid + i * 512;
    int n = gi >> 4, c8 = gi & 15;
    uint4 o = reinterpret_cast<const uint4*>(Wa16)[gi];
    *reinterpret_cast<uint4*>(&WL[n * 128 + ((c8 ^ (n & 15)) * 8)]) = o;
  }

  // ---- phase A: aggregate this wave's 16 nodes ----
  const float s = 1.0f + eps[0];
  for (int i = 0; i < 16; ++i) {
    const int hrow = w * 16 + i;
    const int node = row0 + hrow;
    if (node < NN) {
      float acc[8];
      #pragma unroll
      for (int k = 0; k < 8; ++k) acc[k] = 0.f;
      const int beg = node << 6;
      const int end = beg + cnt[node];
      for (int e = beg; e < end; e += 16) {
        uint4 v[4];
        #pragma unroll
        for (int k = 0; k < 4; ++k) {
          int ee = e + g + 4 * k;
          const unsigned short* prow = (ee < end) ? (Xin + (size_t)csr[ee] * DDIM) : zrow;
          v[k] = *reinterpret_cast<const uint4*>(prow + c * 8);
        }
        __builtin_amdgcn_sched_barrier(0);   // keep all 4 gathers in flight
        #pragma unroll
        for (int k = 0; k < 4; ++k) {
          acc[0] += bf2f((unsigned short)(v[k].x & 0xffff));
          acc[1] += bf2f((unsigned short)(v[k].x >> 16));
          acc[2] += bf2f((unsigned short)(v[k].y & 0xffff));
          acc[3] += bf2f((unsigned short)(v[k].y >> 16));
          acc[4] += bf2f((unsigned short)(v[k].z & 0xffff));
          acc[5] += bf2f((unsigned short)(v[k].z >> 16));
          acc[6] += bf2f((unsigned short)(v[k].w & 0xffff));
          acc[7] += bf2f((unsigned short)(v[k].w >> 16));
        }
      }
      #pragma unroll
      for (int k = 0; k < 8; ++k) acc[k] += __shfl_xor(acc[k], 16, 64);
      #pragma unroll
      for (int k = 0; k < 8; ++k) acc[k] += __shfl_xor(acc[k], 32, 64);
      uint4 sv = *reinterpret_cast<const uint4*>(Xin + (size_t)node * DDIM + c * 8);
      acc[0] += s * bf2f((unsigned short)(sv.x & 0xffff));
      acc[1] += s * bf2f((unsigned short)(sv.x >> 16));
      acc[2] += s * bf2f((unsigned short)(sv.y & 0xffff));
      acc[3] += s * bf2f((unsigned short)(sv.y >> 16));
      acc[4] += s * bf2f((unsigned short)(sv.z & 0xffff));
      acc[5] += s * bf2f((unsigned short)(sv.z >> 16));
      acc[6] += s * bf2f((unsigned short)(sv.w & 0xffff));
      acc[7] += s * bf2f((unsigned short)(sv.w >> 16));
      if (g == 0) {
        uint4 o;
        o.x = f2bf(acc[0]) | ((unsigned)f2bf(acc[1]) << 16);
        o.y = f2bf(acc[2]) | ((unsigned)f2bf(acc[3]) << 16);
        o.z = f2bf(acc[4]) | ((unsigned)f2bf(acc[5]) << 16);
        o.w = f2bf(acc[6]) | ((unsigned)f2bf(acc[7]) << 16);
        *reinterpret_cast<uint4*>(&AH[hrow * 128 + ((c ^ (hrow & 15)) * 8)]) = o;
      }
    } else if (g == 0) {
      uint4 z = make_uint4(0u, 0u, 0u, 0u);
      *reinterpret_cast<uint4*>(&AH[hrow * 128 + ((c ^ (hrow & 15)) * 8)]) = z;
    }
  }
  __syncthreads();   // WL(Wa) complete everywhere; AH rows are wave-local

  const int m = lane & 15, q = lane >> 4;

  // ---- GEMM1: A from AH (own rows), B = Wa ----
  f32x4 acc1[8];
  #pragma unroll
  for (int nt = 0; nt < 8; ++nt) acc1[nt] = (f32x4){0.f, 0.f, 0.f, 0.f};
  const int hrowA = w * 16 + m;
  #pragma unroll
  for (int ks = 0; ks < 4; ++ks) {
    bf16x8 a = *reinterpret_cast<const bf16x8*>(&AH[hrowA * 128 + (((ks * 4 + q) ^ m) * 8)]);
    #pragma unroll
    for (int nt = 0; nt < 8; ++nt) {
      int n = nt * 16 + m;
      bf16x8 b = *reinterpret_cast<const bf16x8*>(&WL[n * 128 + (((ks * 4 + q) ^ (n & 15)) * 8)]);
      acc1[nt] = __builtin_amdgcn_mfma_f32_16x16x32_bf16(a, b, acc1[nt], 0, 0, 0);
    }
  }

  // ---- epilogue 1: bias + relu -> AH (own rows; after own A-reads, program order) ----
  #pragma unroll
  for (int nt = 0; nt < 8; ++nt) {
    int col = nt * 16 + m;
    float bias = Ba[col];
    #pragma unroll
    for (int reg = 0; reg < 4; ++reg) {
      float v = fmaxf(acc1[nt][reg] + bias, 0.f);
      int hrow = w * 16 + q * 4 + reg;
      AH[hrow * 128 + ((((col >> 3) ^ (hrow & 15)) << 3) + (col & 7))] = f2bf(v);
    }
  }
  __syncthreads();   // all GEMM1 WL-reads done => safe to overwrite WL

  // stage Wb
  #pragma unroll
  for (int i = 0; i < 4; ++i) {
    int gi = tid + i * 512;
    int n = gi >> 4, c8 = gi & 15;
    uint4 o = reinterpret_cast<const uint4*>(Wb16)[gi];
    *reinterpret_cast<uint4*>(&WL[n * 128 + ((c8 ^ (n & 15)) * 8)]) = o;
  }
  __syncthreads();

  // ---- GEMM2: A from AH (hidden, own rows), B = Wb ----
  f32x4 acc2[8];
  #pragma unroll
  for (int nt = 0; nt < 8; ++nt) acc2[nt] = (f32x4){0.f, 0.f, 0.f, 0.f};
  #pragma unroll
  for (int ks = 0; ks < 4; ++ks) {
    bf16x8 a = *reinterpret_cast<const bf16x8*>(&AH[hrowA * 128 + (((ks * 4 + q) ^ m) * 8)]);
    #pragma unroll
    for (int nt = 0; nt < 8; ++nt) {
      int n = nt * 16 + m;
      bf16x8 b = *reinterpret_cast<const bf16x8*>(&WL[n * 128 + (((ks * 4 + q) ^ (n & 15)) * 8)]);
      acc2[nt] = __builtin_amdgcn_mfma_f32_16x16x32_bf16(a, b, acc2[nt], 0, 0, 0);
    }
  }

  // ---- epilogue 2: bias (+relu) -> global ----
  #pragma unroll
  for (int nt = 0; nt < 8; ++nt) {
    int col = nt * 16 + m;
    float bias = Bb[col];
    #pragma unroll
    for (int reg = 0; reg < 4; ++reg) {
      int grow = row0 + w * 16 + q * 4 + reg;
      if (grow >= NN) continue;
      float v = acc2[nt][reg] + bias;
      if (RELU_OUT) v = fmaxf(v, 0.f);
      if (BF16_OUT)
        reinterpret_cast<unsigned short*>(Yout)[(size_t)grow * DDIM + col] = f2bf(v);
      else
        reinterpret_cast<float*>(Yout)[(size_t)grow * DDIM + col] = v;
    }
  }
}

extern "C" void kernel_launch(void* const* d_in, const int* in_sizes, int n_in,
                              void* d_out, int out_size, void* d_ws, size_t ws_size,
                              hipStream_t stream)
{
  const float* feat = (const float*)d_in[0];
  const int*   ei   = (const int*)d_in[1];
  const float* w1a  = (const float*)d_in[2];
  const float* b1a  = (const float*)d_in[3];
  const float* w1b  = (const float*)d_in[4];
  const float* b1b  = (const float*)d_in[5];
  const float* eps1 = (const float*)d_in[6];
  const float* w2a  = (const float*)d_in[7];
  const float* b2a  = (const float*)d_in[8];
  const float* w2b  = (const float*)d_in[9];
  const float* b2b  = (const float*)d_in[10];
  const float* eps2 = (const float*)d_in[11];
  float* out = (float*)d_out;

  const int* src = ei;        // edge_index[0]
  const int* dst = ei + EE;   // edge_index[1]

  // workspace layout (zrow + cnt contiguous for one memset)
  char* w = (char*)d_ws;
  unsigned short* zrow = (unsigned short*)w;  w += 256;                                   // 256 zero bytes
  int* cnt  = (int*)w;                        w += ((NN * 4 + 255) & ~255);
  int* csr  = (int*)w;                        w += (((size_t)NN * CAP * 4 + 255) & ~255); // 12.8 MB buckets
  unsigned short* W16 = (unsigned short*)w;   w += ((4 * 128 * 128 * 2 + 255) & ~255);
  unsigned short* Xb = (unsigned short*)w;    w += ((size_t)NN * DDIM * 2 + 255) & ~255;  // featb
  unsigned short* X1 = (unsigned short*)w;    w += ((size_t)NN * DDIM * 2 + 255) & ~255;  // layer-1 out (bf16)

  const unsigned short* W1a16 = W16;
  const unsigned short* W1b16 = W16 + 16384;
  const unsigned short* W2a16 = W16 + 2 * 16384;
  const unsigned short* W2b16 = W16 + 3 * 16384;

  const int fused_blocks = (NN + 127) / 128;      // 391

  // ---- zero cnt+zrow, then prep (cast || wconv || bucket-CSR fill) ----
  hipMemsetAsync(zrow, 0, 256 + NN * sizeof(int), stream);
  k_prep<<<PREP_BLOCKS, 256, 0, stream>>>(feat, w1a, w1b, w2a, w2b, src, dst,
                                          Xb, W16, cnt, csr);

  // ---- layer 1: agg+MLP fused (reads Xb, writes X1) ----
  k_fused<1, 1><<<fused_blocks, 512, 0, stream>>>(Xb, cnt, csr, eps1, zrow,
                                                  W1a16, b1a, W1b16, b1b, (void*)X1);
  // ---- layer 2: agg+MLP fused (reads X1, writes out fp32) ----
  k_fused<0, 0><<<fused_blocks, 512, 0, stream>>>(X1, cnt, csr, eps2, zrow,
                                                  W2a16, b2a, W2b16, b2b, (void*)out);
}

// Round 13
// 237.854 us; speedup vs baseline: 1.1775x; 1.1775x over previous
//
#include <hip/hip_runtime.h>
#include <hip/hip_bf16.h>
#include <stddef.h>

#define NN 50000
#define EE 800000
#define DDIM 128
#define CAP 64                    // bucket capacity (Poisson(16): P(deg>64) ~ 3e-20)

// k_prep grid partition: feat-cast | weight-conv | bucket-CSR fill (overlapped)
#define CAST_BLOCKS 3125          // NN*DDIM/8 / 256 exactly
#define WCONV_BLOCKS 32           // 4*128*128/8 / 256 exactly
#define FILL_BLOCKS 782           // ceil(EE/4/256)
#define PREP_BLOCKS (CAST_BLOCKS + WCONV_BLOCKS + FILL_BLOCKS)

typedef short bf16x8 __attribute__((ext_vector_type(8)));
typedef float f32x4  __attribute__((ext_vector_type(4)));

__device__ __forceinline__ float bf2f(unsigned short u) {
  union { unsigned int i; float f; } v; v.i = ((unsigned int)u) << 16; return v.f;
}
__device__ __forceinline__ unsigned short f2bf(float f) {
  __hip_bfloat16 h = __float2bfloat16(f);
  return *reinterpret_cast<unsigned short*>(&h);
}
__device__ __forceinline__ uint4 pack8(const float4 a, const float4 b) {
  uint4 o;
  o.x = f2bf(a.x) | ((unsigned)f2bf(a.y) << 16);
  o.y = f2bf(a.z) | ((unsigned)f2bf(a.w) << 16);
  o.z = f2bf(b.x) | ((unsigned)f2bf(b.y) << 16);
  o.w = f2bf(b.z) | ((unsigned)f2bf(b.w) << 16);
  return o;
}

// ---------------- prep: feat cast || weight conversion || bucket-CSR fill ----------------
// The latency-bound fill section overlaps with the BW-bound cast on the same CUs.
// cnt must be pre-zeroed (hipMemsetAsync before this kernel).
__global__ __launch_bounds__(256) void k_prep(const float* __restrict__ feat,
                                              const float* __restrict__ w1a,
                                              const float* __restrict__ w1b,
                                              const float* __restrict__ w2a,
                                              const float* __restrict__ w2b,
                                              const int* __restrict__ src,
                                              const int* __restrict__ dst,
                                              unsigned short* __restrict__ Xb,
                                              unsigned short* __restrict__ W16,
                                              int* __restrict__ cnt,
                                              int* __restrict__ csr)
{
  const int b = blockIdx.x, tid = threadIdx.x;
  if (b < CAST_BLOCKS) {
    int t = b * 256 + tid;                       // 800000 exact
    const float4* p = reinterpret_cast<const float4*>(feat) + (size_t)t * 2;
    reinterpret_cast<uint4*>(Xb)[t] = pack8(p[0], p[1]);
  } else if (b < CAST_BLOCKS + WCONV_BLOCKS) {
    int i = (b - CAST_BLOCKS) * 256 + tid;       // 0..8191, 8 floats each
    int which = i >> 11, off = i & 2047;
    const float* wp = (which == 0) ? w1a : (which == 1) ? w1b : (which == 2) ? w2a : w2b;
    const float4* p = reinterpret_cast<const float4*>(wp + off * 8);
    reinterpret_cast<uint4*>(W16 + which * 16384)[off] = pack8(p[0], p[1]);
  } else {
    int t = (b - CAST_BLOCKS - WCONV_BLOCKS) * 256 + tid;
    if (t < EE / 4) {
      int4 s4 = reinterpret_cast<const int4*>(src)[t];
      int4 d4 = reinterpret_cast<const int4*>(dst)[t];
      int p;
      p = atomicAdd(&cnt[d4.x], 1); csr[(d4.x << 6) + p] = s4.x;
      p = atomicAdd(&cnt[d4.y], 1); csr[(d4.y << 6) + p] = s4.y;
      p = atomicAdd(&cnt[d4.z], 1); csr[(d4.z << 6) + p] = s4.z;
      p = atomicAdd(&cnt[d4.w], 1); csr[(d4.w << 6) + p] = s4.w;
    }
  }
}

// ---------------- aggregation: 4 neighbor rows per gather instruction ----------------
// A[n] = (1+eps)*X[n] + sum_{s in N(n)} X[s]; one wave per node.
// lane = (g = lane>>4, c = lane&15): group g handles edge-slot g of each 4-edge
// quad; chunk c covers columns c*8..c*8+7 (16B). One uint4 gather = 4 rows = 1KB.
__global__ __launch_bounds__(256) void k_gin_agg(const unsigned short* __restrict__ Xb,
                                                 const int* __restrict__ cnt,
                                                 const int* __restrict__ csr,
                                                 const float* __restrict__ eps,
                                                 const unsigned short* __restrict__ zrow,
                                                 unsigned short* __restrict__ Ab)
{
  int node = blockIdx.x * 4 + (threadIdx.x >> 6);
  if (node >= NN) return;
  const int lane = threadIdx.x & 63;
  const int g = lane >> 4;          // edge-slot group 0..3
  const int c = lane & 15;          // column chunk (8 bf16 = 16B)

  float acc[8];
  #pragma unroll
  for (int k = 0; k < 8; ++k) acc[k] = 0.f;

  const int beg = node << 6;
  const int end = beg + cnt[node];
  for (int e = beg; e < end; e += 16) {
    uint4 v[4];
    #pragma unroll
    for (int k = 0; k < 4; ++k) {
      int ee = e + g + 4 * k;
      const unsigned short* prow = (ee < end) ? (Xb + (size_t)csr[ee] * DDIM) : zrow;
      v[k] = *reinterpret_cast<const uint4*>(prow + c * 8);
    }
    __builtin_amdgcn_sched_barrier(0);   // keep all 4 gathers in flight before use
    #pragma unroll
    for (int k = 0; k < 4; ++k) {
      acc[0] += bf2f((unsigned short)(v[k].x & 0xffff));
      acc[1] += bf2f((unsigned short)(v[k].x >> 16));
      acc[2] += bf2f((unsigned short)(v[k].y & 0xffff));
      acc[3] += bf2f((unsigned short)(v[k].y >> 16));
      acc[4] += bf2f((unsigned short)(v[k].z & 0xffff));
      acc[5] += bf2f((unsigned short)(v[k].z >> 16));
      acc[6] += bf2f((unsigned short)(v[k].w & 0xffff));
      acc[7] += bf2f((unsigned short)(v[k].w >> 16));
    }
  }

  // butterfly reduce across the 4 groups (lanes differing in bits 4,5)
  #pragma unroll
  for (int k = 0; k < 8; ++k) acc[k] += __shfl_xor(acc[k], 16, 64);
  #pragma unroll
  for (int k = 0; k < 8; ++k) acc[k] += __shfl_xor(acc[k], 32, 64);

  // self term: (1+eps) * X[node]
  const float s = 1.0f + eps[0];
  uint4 sv = *reinterpret_cast<const uint4*>(Xb + (size_t)node * DDIM + c * 8);
  acc[0] += s * bf2f((unsigned short)(sv.x & 0xffff));
  acc[1] += s * bf2f((unsigned short)(sv.x >> 16));
  acc[2] += s * bf2f((unsigned short)(sv.y & 0xffff));
  acc[3] += s * bf2f((unsigned short)(sv.y >> 16));
  acc[4] += s * bf2f((unsigned short)(sv.z & 0xffff));
  acc[5] += s * bf2f((unsigned short)(sv.z >> 16));
  acc[6] += s * bf2f((unsigned short)(sv.w & 0xffff));
  acc[7] += s * bf2f((unsigned short)(sv.w >> 16));

  if (g == 0) {
    uint4 o;
    o.x = f2bf(acc[0]) | ((unsigned)f2bf(acc[1]) << 16);
    o.y = f2bf(acc[2]) | ((unsigned)f2bf(acc[3]) << 16);
    o.z = f2bf(acc[4]) | ((unsigned)f2bf(acc[5]) << 16);
    o.w = f2bf(acc[6]) | ((unsigned)f2bf(acc[7]) << 16);
    *reinterpret_cast<uint4*>(Ab + (size_t)node * DDIM + c * 8) = o;
  }
}

// ---------------- fused MLP: Y = [relu]( relu(X@Wa^T+ba) @ Wb^T + bb ) ----------------
// 128-row tile, 512 threads = 8 waves, MFMA 16x16x32 bf16, pre-converted bf16 weights.
// Single 32KB weight buffer reused for Wa then Wb; LDS 64KB -> 2 blocks/CU (16 waves).
template<int RELU_OUT, int BF16_OUT>
__global__ __launch_bounds__(512) void k_mlp(const unsigned short* __restrict__ Xb,
                                             const unsigned short* __restrict__ Wa16,
                                             const float* __restrict__ Ba,
                                             const unsigned short* __restrict__ Wb16,
                                             const float* __restrict__ Bb,
                                             void* __restrict__ Yout)
{
  __shared__ unsigned short WL[128 * 128];   // weight buffer (Wa, then Wb)
  __shared__ unsigned short HL[128 * 128];   // hidden tile (128 rows)
  const int tid = threadIdx.x;
  const int row0 = blockIdx.x * 128;

  // stage Wa: 2048 16B-granules, swizzle granule-col ^= (row&15)
  #pragma unroll
  for (int i = 0; i < 4; ++i) {
    int g = tid + i * 512;
    int n = g >> 4, c8 = g & 15;
    uint4 o = reinterpret_cast<const uint4*>(Wa16)[g];
    *reinterpret_cast<uint4*>(&WL[n * 128 + ((c8 ^ (n & 15)) * 8)]) = o;
  }
  __syncthreads();

  const int w = tid >> 6, lane = tid & 63;   // w: 0..7 -> rows w*16..w*16+15
  const int m = lane & 15, q = lane >> 4;

  // ---- GEMM1: A-fragments direct from global bf16 ----
  f32x4 acc[8];
  #pragma unroll
  for (int nt = 0; nt < 8; ++nt) acc[nt] = (f32x4){0.f, 0.f, 0.f, 0.f};

  int arow = row0 + w * 16 + m;
  if (arow >= NN) arow = NN - 1;               // clamp; stores are guarded
  const unsigned short* abase = Xb + (size_t)arow * DDIM + q * 8;
  #pragma unroll
  for (int ks = 0; ks < 4; ++ks) {
    bf16x8 a = *reinterpret_cast<const bf16x8*>(abase + ks * 32);
    #pragma unroll
    for (int nt = 0; nt < 8; ++nt) {
      int n = nt * 16 + m;
      bf16x8 b = *reinterpret_cast<const bf16x8*>(&WL[n * 128 + (((ks * 4 + q) ^ (n & 15)) * 8)]);
      acc[nt] = __builtin_amdgcn_mfma_f32_16x16x32_bf16(a, b, acc[nt], 0, 0, 0);
    }
  }

  // ---- epilogue 1: bias + relu -> HL (bf16, swizzled scalar writes) ----
  #pragma unroll
  for (int nt = 0; nt < 8; ++nt) {
    int col = nt * 16 + m;
    float bias = Ba[col];
    #pragma unroll
    for (int reg = 0; reg < 4; ++reg) {
      float v = fmaxf(acc[nt][reg] + bias, 0.f);
      int hrow = w * 16 + q * 4 + reg;       // 0..127
      HL[hrow * 128 + ((((col >> 3) ^ (hrow & 15)) << 3) + (col & 7))] = f2bf(v);
    }
  }
  __syncthreads();   // GEMM1 WL-reads done everywhere; HL complete

  // stage Wb over WL
  #pragma unroll
  for (int i = 0; i < 4; ++i) {
    int g = tid + i * 512;
    int n = g >> 4, c8 = g & 15;
    uint4 o = reinterpret_cast<const uint4*>(Wb16)[g];
    *reinterpret_cast<uint4*>(&WL[n * 128 + ((c8 ^ (n & 15)) * 8)]) = o;
  }
  __syncthreads();

  // ---- GEMM2: A from HL, B from WL ----
  f32x4 acc2[8];
  #pragma unroll
  for (int nt = 0; nt < 8; ++nt) acc2[nt] = (f32x4){0.f, 0.f, 0.f, 0.f};

  const int hrowA = w * 16 + m;
  #pragma unroll
  for (int ks = 0; ks < 4; ++ks) {
    bf16x8 a = *reinterpret_cast<const bf16x8*>(&HL[hrowA * 128 + (((ks * 4 + q) ^ (hrowA & 15)) * 8)]);
    #pragma unroll
    for (int nt = 0; nt < 8; ++nt) {
      int n = nt * 16 + m;
      bf16x8 b = *reinterpret_cast<const bf16x8*>(&WL[n * 128 + (((ks * 4 + q) ^ (n & 15)) * 8)]);
      acc2[nt] = __builtin_amdgcn_mfma_f32_16x16x32_bf16(a, b, acc2[nt], 0, 0, 0);
    }
  }

  // ---- epilogue 2: bias (+relu) -> global ----
  #pragma unroll
  for (int nt = 0; nt < 8; ++nt) {
    int col = nt * 16 + m;
    float bias = Bb[col];
    #pragma unroll
    for (int reg = 0; reg < 4; ++reg) {
      int grow = row0 + w * 16 + q * 4 + reg;
      if (grow >= NN) continue;
      float v = acc2[nt][reg] + bias;
      if (RELU_OUT) v = fmaxf(v, 0.f);
      if (BF16_OUT)
        reinterpret_cast<unsigned short*>(Yout)[(size_t)grow * DDIM + col] = f2bf(v);
      else
        reinterpret_cast<float*>(Yout)[(size_t)grow * DDIM + col] = v;
    }
  }
}

extern "C" void kernel_launch(void* const* d_in, const int* in_sizes, int n_in,
                              void* d_out, int out_size, void* d_ws, size_t ws_size,
                              hipStream_t stream)
{
  const float* feat = (const float*)d_in[0];
  const int*   ei   = (const int*)d_in[1];
  const float* w1a  = (const float*)d_in[2];
  const float* b1a  = (const float*)d_in[3];
  const float* w1b  = (const float*)d_in[4];
  const float* b1b  = (const float*)d_in[5];
  const float* eps1 = (const float*)d_in[6];
  const float* w2a  = (const float*)d_in[7];
  const float* b2a  = (const float*)d_in[8];
  const float* w2b  = (const float*)d_in[9];
  const float* b2b  = (const float*)d_in[10];
  const float* eps2 = (const float*)d_in[11];
  float* out = (float*)d_out;

  const int* src = ei;        // edge_index[0]
  const int* dst = ei + EE;   // edge_index[1]

  // workspace layout (zrow + cnt contiguous for one memset)
  char* w = (char*)d_ws;
  unsigned short* zrow = (unsigned short*)w;  w += 256;                                   // 256 zero bytes
  int* cnt  = (int*)w;                        w += ((NN * 4 + 255) & ~255);
  int* csr  = (int*)w;                        w += (((size_t)NN * CAP * 4 + 255) & ~255); // 12.8 MB buckets
  unsigned short* W16 = (unsigned short*)w;   w += ((4 * 128 * 128 * 2 + 255) & ~255);
  unsigned short* Xb = (unsigned short*)w;    w += ((size_t)NN * DDIM * 2 + 255) & ~255;  // featb
  unsigned short* Ab = (unsigned short*)w;    w += ((size_t)NN * DDIM * 2 + 255) & ~255;  // agg out

  const unsigned short* W1a16 = W16;
  const unsigned short* W1b16 = W16 + 16384;
  const unsigned short* W2a16 = W16 + 2 * 16384;
  const unsigned short* W2b16 = W16 + 3 * 16384;

  const int agg_blocks  = (NN + 3) / 4;           // 12500
  const int mlp_blocks  = (NN + 127) / 128;       // 391

  // ---- zero cnt+zrow, then prep (cast || wconv || bucket-CSR fill overlapped) ----
  hipMemsetAsync(zrow, 0, 256 + NN * sizeof(int), stream);
  k_prep<<<PREP_BLOCKS, 256, 0, stream>>>(feat, w1a, w1b, w2a, w2b, src, dst,
                                          Xb, W16, cnt, csr);

  // ---- layer 1 ----
  k_gin_agg<<<agg_blocks, 256, 0, stream>>>(Xb, cnt, csr, eps1, zrow, Ab);
  k_mlp<1, 1><<<mlp_blocks, 512, 0, stream>>>(Ab, W1a16, b1a, W1b16, b1b, (void*)Xb); // x1 (bf16) overwrites featb

  // ---- layer 2 ----
  k_gin_agg<<<agg_blocks, 256, 0, stream>>>(Xb, cnt, csr, eps2, zrow, Ab);
  k_mlp<0, 0><<<mlp_blocks, 512, 0, stream>>>(Ab, W2a16, b2a, W2b16, b2b, (void*)out);
}